// Round 10
// baseline (163.801 us; speedup 1.0000x reference)
//
#include <hip/hip_runtime.h>

typedef short s16x8 __attribute__((ext_vector_type(8)));
typedef float f32x4 __attribute__((ext_vector_type(4)));
typedef float f32x16 __attribute__((ext_vector_type(16)));
typedef unsigned u32x4 __attribute__((ext_vector_type(4)));

#define BB 4
#define NN 4096
#define LOG2E 1.4426950408889634f

__device__ __forceinline__ unsigned short f2bf(float f) {
    unsigned int u = __builtin_bit_cast(unsigned int, f);
    u += 0x7fff + ((u >> 16) & 1);   // RNE
    return (unsigned short)(u >> 16);
}

// pack two f32 -> bf16x2 (truncation) in one v_perm; low half = first arg
__device__ __forceinline__ unsigned pk2(float lo, float hi) {
    return __builtin_amdgcn_perm(__builtin_bit_cast(unsigned, hi),
                                 __builtin_bit_cast(unsigned, lo), 0x07060302u);
}

// swap lanes[32:63] of a with lanes[0:31] of b  (no volatile: schedulable)
__device__ __forceinline__ void pl32swap(unsigned &a, unsigned &b) {
    asm("v_permlane32_swap_b32 %0, %1" : "+v"(a), "+v"(b));
}

// ---------------------------------------------------------------------------
// Projection via MFMA (unchanged from R9). Outputs: Qw,Kw [b][n][16] padded;
// Vc chunked [b][j=n>>3][c][n&7] for coalesced PV fragment loads.
// ---------------------------------------------------------------------------
__global__ __launch_bounds__(256) void proj_kernel(
    const float* __restrict__ x,
    const float* __restrict__ Wq, const float* __restrict__ bq,
    const float* __restrict__ Wk, const float* __restrict__ bk,
    const float* __restrict__ Wv, const float* __restrict__ bv,
    unsigned short* __restrict__ Qw, unsigned short* __restrict__ Kw,
    unsigned short* __restrict__ Vc)
{
    __shared__ __attribute__((aligned(16))) unsigned short sW[80 * 72];
    __shared__ __attribute__((aligned(16))) unsigned short xT[64 * 72]; // reused as sV
    __shared__ float sb[80];

    int tid = threadIdx.x;
    int b  = blockIdx.x >> 6;
    int n0 = (blockIdx.x & 63) << 6;

    for (int i = tid; i < 1280; i += 256) {
        int o = i >> 4, c4 = (i & 15) << 2;
        const float* src = (o < 8) ? &Wq[o * 64 + c4]
                         : ((o < 16) ? &Wk[(o - 8) * 64 + c4]
                                     : &Wv[(o - 16) * 64 + c4]);
        float4 v = *(const float4*)src;
        float sc = (o < 8) ? LOG2E : 1.f;
        sW[o * 72 + c4 + 0] = f2bf(v.x * sc);
        sW[o * 72 + c4 + 1] = f2bf(v.y * sc);
        sW[o * 72 + c4 + 2] = f2bf(v.z * sc);
        sW[o * 72 + c4 + 3] = f2bf(v.w * sc);
    }
    if (tid < 80)
        sb[tid] = (tid < 8) ? bq[tid] * LOG2E
                            : ((tid < 16) ? bk[tid - 8] : bv[tid - 16]);
    for (int i = tid; i < 1024; i += 256) {
        int c = i >> 4, p4 = (i & 15) << 2;
        float4 v = *(const float4*)&x[(((size_t)b * 64 + c) << 12) + n0 + p4];
        xT[(p4 + 0) * 72 + c] = f2bf(v.x);
        xT[(p4 + 1) * 72 + c] = f2bf(v.y);
        xT[(p4 + 2) * 72 + c] = f2bf(v.z);
        xT[(p4 + 3) * 72 + c] = f2bf(v.w);
    }
    __syncthreads();

    int w = tid >> 6, l = tid & 63, g = l >> 4, q16 = l & 15;
    int pix = w * 16 + q16;

    s16x8 bf0 = *(const s16x8*)&xT[pix * 72 + g * 8];
    s16x8 bf1 = *(const s16x8*)&xT[pix * 72 + 32 + g * 8];

    s16x8 a0[5], a1[5];
#pragma unroll
    for (int ot = 0; ot < 5; ++ot) {
        a0[ot] = *(const s16x8*)&sW[(ot * 16 + q16) * 72 + g * 8];
        a1[ot] = *(const s16x8*)&sW[(ot * 16 + q16) * 72 + 32 + g * 8];
    }
    __syncthreads();   // xT frags consumed; recycle as sV

    unsigned short* sV = xT;
    size_t base16 = ((size_t)(b << 12) + n0 + pix) << 4;

#pragma unroll
    for (int ot = 0; ot < 5; ++ot) {
        f32x4 acc = {0.f, 0.f, 0.f, 0.f};
        acc = __builtin_amdgcn_mfma_f32_16x16x32_bf16(a0[ot], bf0, acc, 0, 0, 0);
        acc = __builtin_amdgcn_mfma_f32_16x16x32_bf16(a1[ot], bf1, acc, 0, 0, 0);
#pragma unroll
        for (int r = 0; r < 4; ++r) {
            int orow = ot * 16 + g * 4 + r;
            unsigned short hv = f2bf(acc[r] + sb[orow]);
            if (ot == 0) {
                if (orow < 8) {
                    Qw[base16 + orow] = hv;
                    Qw[base16 + orow + 8] = 0;
                } else {
                    Kw[base16 + orow - 8] = hv;
                    Kw[base16 + orow] = 0;
                }
            } else {
                sV[(orow - 16) * 72 + pix] = hv;
            }
        }
    }
    __syncthreads();

    // chunked V stores: Vc[b][j][c][8], 16B per (j,c)
#pragma unroll
    for (int i = tid; i < 512; i += 256) {
        int jj = i >> 6, c = i & 63;
        u32x4 v = *(const u32x4*)&sV[c * 72 + jj * 8];
        int jglob = ((blockIdx.x & 63) << 3) + jj;
        *(u32x4*)&Vc[(((size_t)b * 512 + jglob) * 64 + c) * 8] = v;
    }
}

// ---------------------------------------------------------------------------
// Flash attention, 32x32x16 MFMA, in-register P, NO LDS/barriers in main
// loop. Static ping-pong prefetch (2 named frag sets, distance 2) +
// SGPR-uniform base addressing (readfirstlane) + loop-invariant voffsets.
// Block = 512 thr = 8 waves = 32 q x 8-way key split.
// ---------------------------------------------------------------------------
template <int REPS>
__global__ __launch_bounds__(512, 2) void attn_t(
    const unsigned short* __restrict__ Qw, const unsigned short* __restrict__ Kw,
    const unsigned short* __restrict__ Vc, const float* __restrict__ x,
    const float* __restrict__ gamma, float* __restrict__ outp)
{
    __shared__ __attribute__((aligned(16))) float sO[64 * 36];
    __shared__ float sL[8 * 32];
    __shared__ float sGL[32];

    int tid = threadIdx.x;
    int w = tid >> 6, l = tid & 63, r31 = l & 31, hi = l >> 5;
    int p = blockIdx.x;
    int xcd = p & 7, kgrp = p >> 3;
    int b = xcd >> 1;
    int n0 = (((kgrp << 1) | (xcd & 1))) << 5;
    float gm = gamma[0];

    // wave-uniform SGPR bases; lane offsets are loop-invariant VGPRs
    unsigned wK = __builtin_amdgcn_readfirstlane((unsigned)w << 14);
    unsigned wV = __builtin_amdgcn_readfirstlane((unsigned)w << 16);
    const char* Kbw = (const char*)Kw + ((size_t)b << 17) + wK;
    const char* Vbw = (const char*)Vc + ((size_t)b << 19) + wV;
    unsigned kvo = ((unsigned)r31 << 5) + ((unsigned)hi << 4);
    unsigned vvo = ((unsigned)hi << 10) + ((unsigned)r31 << 4);

    s16x8 qf = *(const s16x8*)((const char*)Qw + ((size_t)b << 17)
                               + ((size_t)(n0 + r31) << 5) + (hi << 4));

    f32x16 zz;
#pragma unroll
    for (int i = 0; i < 16; ++i) zz[i] = 0.f;

    for (int rep = 0; rep < REPS; ++rep) {
        f32x16 acc0, acc1;
#pragma unroll
        for (int i = 0; i < 16; ++i) { acc0[i] = 0.f; acc1[i] = 0.f; }
        float la = 0.f;

        s16x8 K_a, A0_a, A1_a, B0_a, B1_a;
        s16x8 K_b, A0_b, A1_b, B0_b, B1_b;

#define LOAD(S, CH) do {                                                    \
        K_##S  = *(const s16x8*)(Kbw + kvo + ((CH) << 10));                 \
        const char* vp_ = Vbw + vvo + ((CH) << 12);                         \
        A0_##S = *(const s16x8*)(vp_);                                      \
        B0_##S = *(const s16x8*)(vp_ + 512);                                \
        A1_##S = *(const s16x8*)(vp_ + 2048);                               \
        B1_##S = *(const s16x8*)(vp_ + 2560);                               \
    } while (0)

#define STEP(S) do {                                                        \
        f32x16 E = __builtin_amdgcn_mfma_f32_32x32x16_bf16(K_##S, qf, zz, 0, 0, 0); \
        _Pragma("unroll")                                                   \
        for (int i = 0; i < 16; ++i) E[i] = __builtin_amdgcn_exp2f(E[i]);   \
        la += (((E[0] + E[1]) + (E[2] + E[3])) + ((E[4] + E[5]) + (E[6] + E[7]))) \
            + (((E[8] + E[9]) + (E[10] + E[11])) + ((E[12] + E[13]) + (E[14] + E[15]))); \
        unsigned x0 = pk2(E[0], E[1]),   x1 = pk2(E[2], E[3]);              \
        unsigned x2 = pk2(E[4], E[5]),   x3 = pk2(E[6], E[7]);              \
        unsigned x4 = pk2(E[8], E[9]),   x5 = pk2(E[10], E[11]);            \
        unsigned x6 = pk2(E[12], E[13]), x7 = pk2(E[14], E[15]);            \
        pl32swap(x0, x2); pl32swap(x1, x3);                                 \
        pl32swap(x4, x6); pl32swap(x5, x7);                                 \
        u32x4 u0 = {x0, x1, x2, x3}, u1 = {x4, x5, x6, x7};                 \
        s16x8 pf0 = __builtin_bit_cast(s16x8, u0);                          \
        s16x8 pf1 = __builtin_bit_cast(s16x8, u1);                          \
        acc0 = __builtin_amdgcn_mfma_f32_32x32x16_bf16(A0_##S, pf0, acc0, 0, 0, 0); \
        acc0 = __builtin_amdgcn_mfma_f32_32x32x16_bf16(A1_##S, pf1, acc0, 0, 0, 0); \
        acc1 = __builtin_amdgcn_mfma_f32_32x32x16_bf16(B0_##S, pf0, acc1, 0, 0, 0); \
        acc1 = __builtin_amdgcn_mfma_f32_32x32x16_bf16(B1_##S, pf1, acc1, 0, 0, 0); \
    } while (0)

        LOAD(a, 0);  LOAD(b, 1);
        STEP(a); LOAD(a, 2);   STEP(b); LOAD(b, 3);
        STEP(a); LOAD(a, 4);   STEP(b); LOAD(b, 5);
        STEP(a); LOAD(a, 6);   STEP(b); LOAD(b, 7);
        STEP(a); LOAD(a, 8);   STEP(b); LOAD(b, 9);
        STEP(a); LOAD(a, 10);  STEP(b); LOAD(b, 11);
        STEP(a); LOAD(a, 12);  STEP(b); LOAD(b, 13);
        STEP(a); LOAD(a, 14);  STEP(b); LOAD(b, 15);
        STEP(a); STEP(b);

#undef LOAD
#undef STEP

        // ---- denominators ----
        la += __shfl_xor(la, 32);
        if (l < 32) sL[w * 32 + l] = la;

        // ---- rotation merge into sO (8 bands x 8 channels), stride 36 ----
#pragma unroll
        for (int s = 0; s < 8; ++s) {
            __syncthreads();
#pragma unroll
            for (int B = 0; B < 8; ++B) {
                if (((w + s) & 7) == B) {
                    const int R2 = B & 3;
                    float e0 = (B < 4) ? acc0[R2 * 4 + 0] : acc1[R2 * 4 + 0];
                    float e1 = (B < 4) ? acc0[R2 * 4 + 1] : acc1[R2 * 4 + 1];
                    float e2 = (B < 4) ? acc0[R2 * 4 + 2] : acc1[R2 * 4 + 2];
                    float e3 = (B < 4) ? acc0[R2 * 4 + 3] : acc1[R2 * 4 + 3];
                    float* pp = &sO[(B * 8 + hi * 4) * 36 + r31];
                    if (s == 0) {
                        pp[0] = e0; pp[36] = e1; pp[72] = e2; pp[108] = e3;
                    } else {
                        pp[0] += e0; pp[36] += e1; pp[72] += e2; pp[108] += e3;
                    }
                }
            }
        }
        __syncthreads();

        if (tid < 32) {
            float L = 0.f;
#pragma unroll
            for (int wk2 = 0; wk2 < 8; ++wk2) L += sL[wk2 * 32 + tid];
            sGL[tid] = gm / L;
        }
        __syncthreads();

        // ---- epilogue: 512 threads x one float4 ----
        {
            int c = tid >> 3, qc = tid & 7;
            float4 o4 = *(const float4*)&sO[c * 36 + qc * 4];
            float4 g4 = *(const float4*)&sGL[qc * 4];
            size_t idx = (((size_t)b * 64 + c) << 12) + n0 + qc * 4;
            float4 x4v = *(const float4*)&x[idx];
            o4.x = o4.x * g4.x + x4v.x;
            o4.y = o4.y * g4.y + x4v.y;
            o4.z = o4.z * g4.z + x4v.z;
            o4.w = o4.w * g4.w + x4v.w;
            *(float4*)&outp[idx] = o4;
        }
        if (REPS > 1) __syncthreads();
    }
}

extern "C" void kernel_launch(void* const* d_in, const int* in_sizes, int n_in,
                              void* d_out, int out_size, void* d_ws, size_t ws_size,
                              hipStream_t stream) {
    const float* x     = (const float*)d_in[0];
    const float* Wq    = (const float*)d_in[1];
    const float* bq    = (const float*)d_in[2];
    const float* Wk    = (const float*)d_in[3];
    const float* bk    = (const float*)d_in[4];
    const float* Wv    = (const float*)d_in[5];
    const float* bv    = (const float*)d_in[6];
    const float* gamma = (const float*)d_in[7];
    float* out = (float*)d_out;

    unsigned short* Qw = (unsigned short*)d_ws;          // [B][N][16] bf16 (padded)
    unsigned short* Kw = Qw + (size_t)BB * NN * 16;      // [B][N][16] bf16 (padded)
    unsigned short* Vc = Kw + (size_t)BB * NN * 16;      // [B][N/8][C][8] bf16
    float* scratch = (float*)((char*)d_ws + (size_t)(16 << 20)); // probe sink

    proj_kernel<<<256, 256, 0, stream>>>(x, Wq, bq, Wk, bk, Wv, bv, Qw, Kw, Vc);
    attn_t<1><<<512, 512, 0, stream>>>(Qw, Kw, Vc, x, gamma, out);
    attn_t<4><<<512, 512, 0, stream>>>(Qw, Kw, Vc, x, gamma, scratch);
}

// Round 11
// 33.026 us; speedup vs baseline: 4.9598x; 4.9598x over previous
//
#include <hip/hip_runtime.h>

typedef short s16x8 __attribute__((ext_vector_type(8)));
typedef float f32x4 __attribute__((ext_vector_type(4)));
typedef float f32x16 __attribute__((ext_vector_type(16)));
typedef unsigned u32x4 __attribute__((ext_vector_type(4)));

#define BB 4
#define NN 4096
#define LOG2E 1.4426950408889634f

__device__ __forceinline__ unsigned short f2bf(float f) {
    unsigned int u = __builtin_bit_cast(unsigned int, f);
    u += 0x7fff + ((u >> 16) & 1);   // RNE
    return (unsigned short)(u >> 16);
}

// pack two f32 -> bf16x2 (truncation) in one v_perm; low half = first arg
__device__ __forceinline__ unsigned pk2(float lo, float hi) {
    return __builtin_amdgcn_perm(__builtin_bit_cast(unsigned, hi),
                                 __builtin_bit_cast(unsigned, lo), 0x07060302u);
}

__device__ __forceinline__ void gload16(const void* g, void* l) {
    __builtin_amdgcn_global_load_lds(
        (const __attribute__((address_space(1))) unsigned int*)g,
        (__attribute__((address_space(3))) unsigned int*)l, 16, 0, 0);
}

// swap lanes[32:63] of a with lanes[0:31] of b
__device__ __forceinline__ void pl32swap(unsigned &a, unsigned &b) {
    asm volatile("v_permlane32_swap_b32 %0, %1" : "+v"(a), "+v"(b));
}

// ---------------------------------------------------------------------------
// Projection via MFMA (unchanged, proven). W packed as 80 rows (q 0-7
// pre-scaled by log2e, k 8-15, v 16-79). Outputs (bf16): Qw,Kw [b][n][16]
// (k 8..15 = 0); Vw [b][c][n]. V staged through LDS for coalesced stores.
// ---------------------------------------------------------------------------
__global__ __launch_bounds__(256) void proj_kernel(
    const float* __restrict__ x,
    const float* __restrict__ Wq, const float* __restrict__ bq,
    const float* __restrict__ Wk, const float* __restrict__ bk,
    const float* __restrict__ Wv, const float* __restrict__ bv,
    unsigned short* __restrict__ Qw, unsigned short* __restrict__ Kw,
    unsigned short* __restrict__ Vw)
{
    __shared__ __attribute__((aligned(16))) unsigned short sW[80 * 72];
    __shared__ __attribute__((aligned(16))) unsigned short xT[64 * 72]; // reused as sV
    __shared__ float sb[80];

    int tid = threadIdx.x;
    int b  = blockIdx.x >> 6;
    int n0 = (blockIdx.x & 63) << 6;

    for (int i = tid; i < 1280; i += 256) {
        int o = i >> 4, c4 = (i & 15) << 2;
        const float* src = (o < 8) ? &Wq[o * 64 + c4]
                         : ((o < 16) ? &Wk[(o - 8) * 64 + c4]
                                     : &Wv[(o - 16) * 64 + c4]);
        float4 v = *(const float4*)src;
        float sc = (o < 8) ? LOG2E : 1.f;
        sW[o * 72 + c4 + 0] = f2bf(v.x * sc);
        sW[o * 72 + c4 + 1] = f2bf(v.y * sc);
        sW[o * 72 + c4 + 2] = f2bf(v.z * sc);
        sW[o * 72 + c4 + 3] = f2bf(v.w * sc);
    }
    if (tid < 80)
        sb[tid] = (tid < 8) ? bq[tid] * LOG2E
                            : ((tid < 16) ? bk[tid - 8] : bv[tid - 16]);
    for (int i = tid; i < 1024; i += 256) {
        int c = i >> 4, p4 = (i & 15) << 2;
        float4 v = *(const float4*)&x[(((size_t)b * 64 + c) << 12) + n0 + p4];
        xT[(p4 + 0) * 72 + c] = f2bf(v.x);
        xT[(p4 + 1) * 72 + c] = f2bf(v.y);
        xT[(p4 + 2) * 72 + c] = f2bf(v.z);
        xT[(p4 + 3) * 72 + c] = f2bf(v.w);
    }
    __syncthreads();

    int w = tid >> 6, l = tid & 63, g = l >> 4, q16 = l & 15;
    int pix = w * 16 + q16;

    s16x8 bf0 = *(const s16x8*)&xT[pix * 72 + g * 8];
    s16x8 bf1 = *(const s16x8*)&xT[pix * 72 + 32 + g * 8];

    s16x8 a0[5], a1[5];
#pragma unroll
    for (int ot = 0; ot < 5; ++ot) {
        a0[ot] = *(const s16x8*)&sW[(ot * 16 + q16) * 72 + g * 8];
        a1[ot] = *(const s16x8*)&sW[(ot * 16 + q16) * 72 + 32 + g * 8];
    }
    __syncthreads();   // xT frags consumed; recycle as sV

    unsigned short* sV = xT;
    size_t base16 = ((size_t)(b << 12) + n0 + pix) << 4;

#pragma unroll
    for (int ot = 0; ot < 5; ++ot) {
        f32x4 acc = {0.f, 0.f, 0.f, 0.f};
        acc = __builtin_amdgcn_mfma_f32_16x16x32_bf16(a0[ot], bf0, acc, 0, 0, 0);
        acc = __builtin_amdgcn_mfma_f32_16x16x32_bf16(a1[ot], bf1, acc, 0, 0, 0);
#pragma unroll
        for (int r = 0; r < 4; ++r) {
            int orow = ot * 16 + g * 4 + r;
            unsigned short hv = f2bf(acc[r] + sb[orow]);
            if (ot == 0) {
                if (orow < 8) {
                    Qw[base16 + orow] = hv;
                    Qw[base16 + orow + 8] = 0;
                } else {
                    Kw[base16 + orow - 8] = hv;
                    Kw[base16 + orow] = 0;
                }
            } else {
                sV[(orow - 16) * 72 + pix] = hv;
            }
        }
    }
    __syncthreads();

#pragma unroll
    for (int i = tid; i < 512; i += 256) {
        int c = i >> 3, oct = i & 7;
        u32x4 v = *(const u32x4*)&sV[c * 72 + oct * 8];
        *(u32x4*)&Vw[(((size_t)b * 64 + c) << 12) + n0 + oct * 8] = v;
    }
}

// ---------------------------------------------------------------------------
// Flash attention (R8/R5 proven structure). Block = 1024 thr = 16 waves =
// 2 wq (32 q) x 8 wk (512-key slices); 8 tiles x 512 keys, V in LDS
// (XOR-swizzled, double-buffered via global_load_lds), in-register P.
// R11 deltas: __launch_bounds__(1024) (frees regalloc from 64-VGPR squeeze),
// s_setprio(1) around MFMA clusters (T5).
// ---------------------------------------------------------------------------
__global__ __launch_bounds__(1024) void attn_kernel(
    const unsigned short* __restrict__ Qw, const unsigned short* __restrict__ Kw,
    const unsigned short* __restrict__ Vw, const float* __restrict__ x,
    const float* __restrict__ gamma, float* __restrict__ outp)
{
    // [0,131072)        V tiles: 2 bufs x [64 c][64 chunk16], row stride 1024B
    // [131072,148480)   sO [64 c][68 f32]
    // [148480,150528)   sL [8 wk][64 q]
    // [150528,150784)   sGL [64]
    __shared__ __attribute__((aligned(16))) char smem[150784];
    const int OOFF = 131072, LOFF = 148480, GLOFF = 150528;

    int tid = threadIdx.x;
    int w = tid >> 6, l = tid & 63, r31 = l & 31, hi = l >> 5;
    int wq = w >> 3, wk = w & 7;
    int b  = blockIdx.x >> 6;
    int n0 = (blockIdx.x & 63) << 6;
    float gm = gamma[0];

    // ---- V staging: rows {w, w+16, w+32, w+48}, shared XOR key w&7 ----
    const char* vsrc = (const char*)Vw + ((size_t)b << 19) + ((size_t)w << 13)
                     + ((l ^ (w & 7)) << 4);
    char* vdst = smem + w * 1024;

    // ---- Q fragment (held all kernel) ----
    const char* Qb = (const char*)Qw + ((size_t)b << 17);
    s16x8 qf = *(const s16x8*)(Qb + ((size_t)(n0 + wq * 32 + r31) << 5) + (hi << 4));
    const char* Kb = (const char*)Kw + ((size_t)b << 17)
                   + ((size_t)r31 << 5) + (hi << 4);

    f32x16 acc0, acc1;
#pragma unroll
    for (int i = 0; i < 16; ++i) { acc0[i] = 0.f; acc1[i] = 0.f; }
    float la = 0.f;

    // prologue: stage tile 0 -> buf 0
    gload16(vsrc, vdst);
    gload16(vsrc + (16 << 13), vdst + 16 * 1024);
    gload16(vsrc + (32 << 13), vdst + 32 * 1024);
    gload16(vsrc + (48 << 13), vdst + 48 * 1024);
    __syncthreads();

    for (int t = 0; t < 8; ++t) {
        int buf = t & 1;
        if (t < 7) {
            int bo = (buf ^ 1) << 16;
            const char* vs = vsrc + (size_t)(t + 1) * 1024;
            gload16(vs,              vdst + bo);
            gload16(vs + (16 << 13), vdst + bo + 16 * 1024);
            gload16(vs + (32 << 13), vdst + bo + 32 * 1024);
            gload16(vs + (48 << 13), vdst + bo + 48 * 1024);
        }
        const char* Vt = smem + (buf << 16);

        // prefetch K frags for both 32-key chunks of this tile
        int kk0 = (t << 9) + (wk << 6);
        s16x8 kfA = *(const s16x8*)(Kb + ((size_t)kk0 << 5));
        s16x8 kfB = *(const s16x8*)(Kb + ((size_t)(kk0 + 32) << 5));

#pragma unroll
        for (int ci = 0; ci < 2; ++ci) {
            s16x8 kf = ci ? kfB : kfA;

            f32x16 E;
            {
                f32x16 z;
#pragma unroll
                for (int i = 0; i < 16; ++i) z[i] = 0.f;
                __builtin_amdgcn_s_setprio(1);
                E = __builtin_amdgcn_mfma_f32_32x32x16_bf16(kf, qf, z, 0, 0, 0);
                __builtin_amdgcn_s_setprio(0);
            }
#pragma unroll
            for (int i = 0; i < 16; ++i) E[i] = __builtin_amdgcn_exp2f(E[i]);
            la += (((E[0] + E[1]) + (E[2] + E[3])) + ((E[4] + E[5]) + (E[6] + E[7])))
                + (((E[8] + E[9]) + (E[10] + E[11])) + ((E[12] + E[13]) + (E[14] + E[15])));

            unsigned x0 = pk2(E[0], E[1]),   x1 = pk2(E[2], E[3]);
            unsigned x2 = pk2(E[4], E[5]),   x3 = pk2(E[6], E[7]);
            unsigned x4 = pk2(E[8], E[9]),   x5 = pk2(E[10], E[11]);
            unsigned x6 = pk2(E[12], E[13]), x7 = pk2(E[14], E[15]);
            pl32swap(x0, x2); pl32swap(x1, x3);
            pl32swap(x4, x6); pl32swap(x5, x7);
            u32x4 u0 = {x0, x1, x2, x3}, u1 = {x4, x5, x6, x7};
            s16x8 pf0 = __builtin_bit_cast(s16x8, u0);
            s16x8 pf1 = __builtin_bit_cast(s16x8, u1);

            // V frags: A[row=c][k=key]; chunk j = wk*8 + ci*4 + pair*2 + hi
            int jb = (wk << 3) + (ci << 2);
            int sj0 = (((jb + hi) ^ (r31 & 7)) << 4);
            int sj1 = (((jb + 2 + hi) ^ (r31 & 7)) << 4);
            const char* row_lo = Vt + (r31 << 10);
            const char* row_hi = row_lo + (32 << 10);
            s16x8 vA0 = *(const s16x8*)(row_lo + sj0);
            s16x8 vA1 = *(const s16x8*)(row_lo + sj1);
            s16x8 vB0 = *(const s16x8*)(row_hi + sj0);
            s16x8 vB1 = *(const s16x8*)(row_hi + sj1);

            __builtin_amdgcn_s_setprio(1);
            acc0 = __builtin_amdgcn_mfma_f32_32x32x16_bf16(vA0, pf0, acc0, 0, 0, 0);
            acc0 = __builtin_amdgcn_mfma_f32_32x32x16_bf16(vA1, pf1, acc0, 0, 0, 0);
            acc1 = __builtin_amdgcn_mfma_f32_32x32x16_bf16(vB0, pf0, acc1, 0, 0, 0);
            acc1 = __builtin_amdgcn_mfma_f32_32x32x16_bf16(vB1, pf1, acc1, 0, 0, 0);
            __builtin_amdgcn_s_setprio(0);
        }
        __syncthreads();
    }

    // ---- denominators ----
    la += __shfl_xor(la, 32);
    float* sL = (float*)(smem + LOFF);
    if (l < 32) sL[wk * 64 + wq * 32 + l] = la;

    // ---- rotation merge into sO ----
    float* sO = (float*)(smem + OOFF);
#pragma unroll
    for (int s = 0; s < 8; ++s) {
#pragma unroll
        for (int B = 0; B < 8; ++B) {
            if (((wk + s) & 7) == B) {
                const int R2 = B & 3;
                float e0 = (B < 4) ? acc0[R2 * 4 + 0] : acc1[R2 * 4 + 0];
                float e1 = (B < 4) ? acc0[R2 * 4 + 1] : acc1[R2 * 4 + 1];
                float e2 = (B < 4) ? acc0[R2 * 4 + 2] : acc1[R2 * 4 + 2];
                float e3 = (B < 4) ? acc0[R2 * 4 + 3] : acc1[R2 * 4 + 3];
                float* pp = &sO[(B * 8 + hi * 4) * 68 + wq * 32 + r31];
                if (s == 0) {
                    pp[0] = e0; pp[68] = e1; pp[136] = e2; pp[204] = e3;
                } else {
                    pp[0] += e0; pp[68] += e1; pp[136] += e2; pp[204] += e3;
                }
            }
        }
        __syncthreads();
    }

    float* sGL = (float*)(smem + GLOFF);
    if (tid < 64) {
        float L = 0.f;
#pragma unroll
        for (int wk2 = 0; wk2 < 8; ++wk2) L += sL[wk2 * 64 + tid];
        sGL[tid] = gm / L;
    }
    __syncthreads();

#pragma unroll
    for (int pp = 0; pp < 4; ++pp) {
        int c = pp * 16 + w;
        size_t idx = (((size_t)b * 64 + c) << 12) + n0 + l;
        outp[idx] = sGL[l] * sO[c * 68 + l] + x[idx];
    }
}

extern "C" void kernel_launch(void* const* d_in, const int* in_sizes, int n_in,
                              void* d_out, int out_size, void* d_ws, size_t ws_size,
                              hipStream_t stream) {
    const float* x     = (const float*)d_in[0];
    const float* Wq    = (const float*)d_in[1];
    const float* bq    = (const float*)d_in[2];
    const float* Wk    = (const float*)d_in[3];
    const float* bk    = (const float*)d_in[4];
    const float* Wv    = (const float*)d_in[5];
    const float* bv    = (const float*)d_in[6];
    const float* gamma = (const float*)d_in[7];
    float* out = (float*)d_out;

    unsigned short* Qw = (unsigned short*)d_ws;          // [B][N][16] bf16 (padded)
    unsigned short* Kw = Qw + (size_t)BB * NN * 16;      // [B][N][16] bf16 (padded)
    unsigned short* Vw = Kw + (size_t)BB * NN * 16;      // [B][C][N]  bf16

    proj_kernel<<<256, 256, 0, stream>>>(x, Wq, bq, Wk, bk, Wv, bv, Qw, Kw, Vw);
    attn_kernel<<<256, 1024, 0, stream>>>(Qw, Kw, Vw, x, gamma, out);
}

// Round 12
// 31.856 us; speedup vs baseline: 5.1419x; 1.0367x over previous
//
#include <hip/hip_runtime.h>

typedef short s16x8 __attribute__((ext_vector_type(8)));
typedef float f32x4 __attribute__((ext_vector_type(4)));
typedef float f32x16 __attribute__((ext_vector_type(16)));
typedef unsigned u32x4 __attribute__((ext_vector_type(4)));

#define BB 4
#define NN 4096
#define LOG2E 1.4426950408889634f

__device__ __forceinline__ unsigned short f2bf(float f) {
    unsigned int u = __builtin_bit_cast(unsigned int, f);
    u += 0x7fff + ((u >> 16) & 1);   // RNE
    return (unsigned short)(u >> 16);
}

// pack two f32 -> bf16x2 (truncation) in one v_perm; low half = first arg
__device__ __forceinline__ unsigned pk2(float lo, float hi) {
    return __builtin_amdgcn_perm(__builtin_bit_cast(unsigned, hi),
                                 __builtin_bit_cast(unsigned, lo), 0x07060302u);
}

__device__ __forceinline__ void gload16(const void* g, void* l) {
    __builtin_amdgcn_global_load_lds(
        (const __attribute__((address_space(1))) unsigned int*)g,
        (__attribute__((address_space(3))) unsigned int*)l, 16, 0, 0);
}

// swap lanes[32:63] of a with lanes[0:31] of b
__device__ __forceinline__ void pl32swap(unsigned &a, unsigned &b) {
    asm volatile("v_permlane32_swap_b32 %0, %1" : "+v"(a), "+v"(b));
}

// ---------------------------------------------------------------------------
// Projection via MFMA (unchanged, proven). W packed as 80 rows (q 0-7
// pre-scaled by log2e, k 8-15, v 16-79). Outputs (bf16): Qw,Kw [b][n][16]
// (k 8..15 = 0); Vw [b][c][n]. V staged through LDS for coalesced stores.
// ---------------------------------------------------------------------------
__global__ __launch_bounds__(256) void proj_kernel(
    const float* __restrict__ x,
    const float* __restrict__ Wq, const float* __restrict__ bq,
    const float* __restrict__ Wk, const float* __restrict__ bk,
    const float* __restrict__ Wv, const float* __restrict__ bv,
    unsigned short* __restrict__ Qw, unsigned short* __restrict__ Kw,
    unsigned short* __restrict__ Vw)
{
    __shared__ __attribute__((aligned(16))) unsigned short sW[80 * 72];
    __shared__ __attribute__((aligned(16))) unsigned short xT[64 * 72]; // reused as sV
    __shared__ float sb[80];

    int tid = threadIdx.x;
    int b  = blockIdx.x >> 6;
    int n0 = (blockIdx.x & 63) << 6;

    for (int i = tid; i < 1280; i += 256) {
        int o = i >> 4, c4 = (i & 15) << 2;
        const float* src = (o < 8) ? &Wq[o * 64 + c4]
                         : ((o < 16) ? &Wk[(o - 8) * 64 + c4]
                                     : &Wv[(o - 16) * 64 + c4]);
        float4 v = *(const float4*)src;
        float sc = (o < 8) ? LOG2E : 1.f;
        sW[o * 72 + c4 + 0] = f2bf(v.x * sc);
        sW[o * 72 + c4 + 1] = f2bf(v.y * sc);
        sW[o * 72 + c4 + 2] = f2bf(v.z * sc);
        sW[o * 72 + c4 + 3] = f2bf(v.w * sc);
    }
    if (tid < 80)
        sb[tid] = (tid < 8) ? bq[tid] * LOG2E
                            : ((tid < 16) ? bk[tid - 8] : bv[tid - 16]);
    for (int i = tid; i < 1024; i += 256) {
        int c = i >> 4, p4 = (i & 15) << 2;
        float4 v = *(const float4*)&x[(((size_t)b * 64 + c) << 12) + n0 + p4];
        xT[(p4 + 0) * 72 + c] = f2bf(v.x);
        xT[(p4 + 1) * 72 + c] = f2bf(v.y);
        xT[(p4 + 2) * 72 + c] = f2bf(v.z);
        xT[(p4 + 3) * 72 + c] = f2bf(v.w);
    }
    __syncthreads();

    int w = tid >> 6, l = tid & 63, g = l >> 4, q16 = l & 15;
    int pix = w * 16 + q16;

    s16x8 bf0 = *(const s16x8*)&xT[pix * 72 + g * 8];
    s16x8 bf1 = *(const s16x8*)&xT[pix * 72 + 32 + g * 8];

    s16x8 a0[5], a1[5];
#pragma unroll
    for (int ot = 0; ot < 5; ++ot) {
        a0[ot] = *(const s16x8*)&sW[(ot * 16 + q16) * 72 + g * 8];
        a1[ot] = *(const s16x8*)&sW[(ot * 16 + q16) * 72 + 32 + g * 8];
    }
    __syncthreads();   // xT frags consumed; recycle as sV

    unsigned short* sV = xT;
    size_t base16 = ((size_t)(b << 12) + n0 + pix) << 4;

#pragma unroll
    for (int ot = 0; ot < 5; ++ot) {
        f32x4 acc = {0.f, 0.f, 0.f, 0.f};
        acc = __builtin_amdgcn_mfma_f32_16x16x32_bf16(a0[ot], bf0, acc, 0, 0, 0);
        acc = __builtin_amdgcn_mfma_f32_16x16x32_bf16(a1[ot], bf1, acc, 0, 0, 0);
#pragma unroll
        for (int r = 0; r < 4; ++r) {
            int orow = ot * 16 + g * 4 + r;
            unsigned short hv = f2bf(acc[r] + sb[orow]);
            if (ot == 0) {
                if (orow < 8) {
                    Qw[base16 + orow] = hv;
                    Qw[base16 + orow + 8] = 0;
                } else {
                    Kw[base16 + orow - 8] = hv;
                    Kw[base16 + orow] = 0;
                }
            } else {
                sV[(orow - 16) * 72 + pix] = hv;
            }
        }
    }
    __syncthreads();

#pragma unroll
    for (int i = tid; i < 512; i += 256) {
        int c = i >> 3, oct = i & 7;
        u32x4 v = *(const u32x4*)&sV[c * 72 + oct * 8];
        *(u32x4*)&Vw[(((size_t)b * 64 + c) << 12) + n0 + oct * 8] = v;
    }
}

// ---------------------------------------------------------------------------
// Flash attention (R5 proven structure). Block = 1024 thr = 16 waves =
// 2 wq (32 q) x 8 wk (512-key slices); 8 tiles x 512 keys, V in LDS
// (double-buffered via global_load_lds), in-register P.
// R12 deltas vs R5:
//   * FULL 5-bit XOR V-swizzle (rows w,w+32 key=w; w+16,w+48 key=w+16;
//     read-side ^r31) -> ds_read_b128 spans 32 distinct 16B slots,
//     eliminating the 4-way bank conflict R5 introduced (R8: 4.19M cyc).
//   * ci-chunk order staggered by wave parity -> waves desync trans/MFMA.
// ---------------------------------------------------------------------------
__global__ __launch_bounds__(1024, 4) void attn_kernel(
    const unsigned short* __restrict__ Qw, const unsigned short* __restrict__ Kw,
    const unsigned short* __restrict__ Vw, const float* __restrict__ x,
    const float* __restrict__ gamma, float* __restrict__ outp)
{
    // [0,131072)        V tiles: 2 bufs x [64 c][64 chunk16], row stride 1024B
    // [131072,148480)   sO [64 c][68 f32]
    // [148480,150528)   sL [8 wk][64 q]
    // [150528,150784)   sGL [64]
    __shared__ __attribute__((aligned(16))) char smem[150784];
    const int OOFF = 131072, LOFF = 148480, GLOFF = 150528;

    int tid = threadIdx.x;
    int w = tid >> 6, l = tid & 63, r31 = l & 31, hi = l >> 5;
    int wq = w >> 3, wk = w & 7;
    int b  = blockIdx.x >> 6;
    int n0 = (blockIdx.x & 63) << 6;
    float gm = gamma[0];

    // ---- V staging: rows {w, w+32} use XOR key w; {w+16, w+48} use w+16 ----
    const char* Vb = (const char*)Vw + ((size_t)b << 19);
    const char* vsA = Vb + ((size_t)w << 13)        + ((l ^ w) << 4);
    const char* vsB = Vb + ((size_t)(w + 16) << 13) + ((l ^ (w + 16)) << 4);
    char* vdst = smem + w * 1024;

    // ---- Q fragment (held all kernel) ----
    const char* Qb = (const char*)Qw + ((size_t)b << 17);
    s16x8 qf = *(const s16x8*)(Qb + ((size_t)(n0 + wq * 32 + r31) << 5) + (hi << 4));
    const char* Kb = (const char*)Kw + ((size_t)b << 17)
                   + ((size_t)r31 << 5) + (hi << 4);

    f32x16 acc0, acc1;
#pragma unroll
    for (int i = 0; i < 16; ++i) { acc0[i] = 0.f; acc1[i] = 0.f; }
    float la = 0.f;

    // prologue: stage tile 0 -> buf 0
    gload16(vsA,             vdst);
    gload16(vsB,             vdst + 16 * 1024);
    gload16(vsA + (32 << 13), vdst + 32 * 1024);
    gload16(vsB + (32 << 13), vdst + 48 * 1024);
    __syncthreads();

    for (int t = 0; t < 8; ++t) {
        int buf = t & 1;
        if (t < 7) {
            int bo = (buf ^ 1) << 16;
            size_t so = (size_t)(t + 1) * 1024;
            gload16(vsA + so,             vdst + bo);
            gload16(vsB + so,             vdst + bo + 16 * 1024);
            gload16(vsA + so + (32 << 13), vdst + bo + 32 * 1024);
            gload16(vsB + so + (32 << 13), vdst + bo + 48 * 1024);
        }
        const char* Vt = smem + (buf << 16);

        // prefetch K frags for both 32-key chunks of this tile
        int kk0 = (t << 9) + (wk << 6);
        s16x8 kfA = *(const s16x8*)(Kb + ((size_t)kk0 << 5));
        s16x8 kfB = *(const s16x8*)(Kb + ((size_t)(kk0 + 32) << 5));

        int cfirst = wk & 1;   // stagger: odd waves do ci=1 first
#pragma unroll
        for (int cii = 0; cii < 2; ++cii) {
            int ci = cii ^ cfirst;
            s16x8 kf = ci ? kfB : kfA;

            f32x16 E;
            {
                f32x16 z;
#pragma unroll
                for (int i = 0; i < 16; ++i) z[i] = 0.f;
                E = __builtin_amdgcn_mfma_f32_32x32x16_bf16(kf, qf, z, 0, 0, 0);
            }
#pragma unroll
            for (int i = 0; i < 16; ++i) E[i] = __builtin_amdgcn_exp2f(E[i]);
            la += (((E[0] + E[1]) + (E[2] + E[3])) + ((E[4] + E[5]) + (E[6] + E[7])))
                + (((E[8] + E[9]) + (E[10] + E[11])) + ((E[12] + E[13]) + (E[14] + E[15])));

            unsigned x0 = pk2(E[0], E[1]),   x1 = pk2(E[2], E[3]);
            unsigned x2 = pk2(E[4], E[5]),   x3 = pk2(E[6], E[7]);
            unsigned x4 = pk2(E[8], E[9]),   x5 = pk2(E[10], E[11]);
            unsigned x6 = pk2(E[12], E[13]), x7 = pk2(E[14], E[15]);
            pl32swap(x0, x2); pl32swap(x1, x3);
            pl32swap(x4, x6); pl32swap(x5, x7);
            u32x4 u0 = {x0, x1, x2, x3}, u1 = {x4, x5, x6, x7};
            s16x8 pf0 = __builtin_bit_cast(s16x8, u0);
            s16x8 pf1 = __builtin_bit_cast(s16x8, u1);

            // V frags: A[row=c][k=key]; slot = (chunk16 idx) ^ r31 (full 5-bit)
            int jb = (wk << 3) + (ci << 2);
            int sj0 = (((jb + hi) ^ r31) << 4);
            int sj1 = (((jb + 2 + hi) ^ r31) << 4);
            const char* row_lo = Vt + (r31 << 10);
            const char* row_hi = row_lo + (32 << 10);
            s16x8 vA0 = *(const s16x8*)(row_lo + sj0);
            s16x8 vA1 = *(const s16x8*)(row_lo + sj1);
            s16x8 vB0 = *(const s16x8*)(row_hi + sj0);
            s16x8 vB1 = *(const s16x8*)(row_hi + sj1);

            acc0 = __builtin_amdgcn_mfma_f32_32x32x16_bf16(vA0, pf0, acc0, 0, 0, 0);
            acc0 = __builtin_amdgcn_mfma_f32_32x32x16_bf16(vA1, pf1, acc0, 0, 0, 0);
            acc1 = __builtin_amdgcn_mfma_f32_32x32x16_bf16(vB0, pf0, acc1, 0, 0, 0);
            acc1 = __builtin_amdgcn_mfma_f32_32x32x16_bf16(vB1, pf1, acc1, 0, 0, 0);
        }
        __syncthreads();
    }

    // ---- denominators ----
    la += __shfl_xor(la, 32);
    float* sL = (float*)(smem + LOFF);
    if (l < 32) sL[wk * 64 + wq * 32 + l] = la;

    // ---- rotation merge into sO ----
    float* sO = (float*)(smem + OOFF);
#pragma unroll
    for (int s = 0; s < 8; ++s) {
#pragma unroll
        for (int B = 0; B < 8; ++B) {
            if (((wk + s) & 7) == B) {
                const int R2 = B & 3;
                float e0 = (B < 4) ? acc0[R2 * 4 + 0] : acc1[R2 * 4 + 0];
                float e1 = (B < 4) ? acc0[R2 * 4 + 1] : acc1[R2 * 4 + 1];
                float e2 = (B < 4) ? acc0[R2 * 4 + 2] : acc1[R2 * 4 + 2];
                float e3 = (B < 4) ? acc0[R2 * 4 + 3] : acc1[R2 * 4 + 3];
                float* pp = &sO[(B * 8 + hi * 4) * 68 + wq * 32 + r31];
                if (s == 0) {
                    pp[0] = e0; pp[68] = e1; pp[136] = e2; pp[204] = e3;
                } else {
                    pp[0] += e0; pp[68] += e1; pp[136] += e2; pp[204] += e3;
                }
            }
        }
        __syncthreads();
    }

    float* sGL = (float*)(smem + GLOFF);
    if (tid < 64) {
        float L = 0.f;
#pragma unroll
        for (int wk2 = 0; wk2 < 8; ++wk2) L += sL[wk2 * 64 + tid];
        sGL[tid] = gm / L;
    }
    __syncthreads();

#pragma unroll
    for (int pp = 0; pp < 4; ++pp) {
        int c = pp * 16 + w;
        size_t idx = (((size_t)b * 64 + c) << 12) + n0 + l;
        outp[idx] = sGL[l] * sO[c * 68 + l] + x[idx];
    }
}

extern "C" void kernel_launch(void* const* d_in, const int* in_sizes, int n_in,
                              void* d_out, int out_size, void* d_ws, size_t ws_size,
                              hipStream_t stream) {
    const float* x     = (const float*)d_in[0];
    const float* Wq    = (const float*)d_in[1];
    const float* bq    = (const float*)d_in[2];
    const float* Wk    = (const float*)d_in[3];
    const float* bk    = (const float*)d_in[4];
    const float* Wv    = (const float*)d_in[5];
    const float* bv    = (const float*)d_in[6];
    const float* gamma = (const float*)d_in[7];
    float* out = (float*)d_out;

    unsigned short* Qw = (unsigned short*)d_ws;          // [B][N][16] bf16 (padded)
    unsigned short* Kw = Qw + (size_t)BB * NN * 16;      // [B][N][16] bf16 (padded)
    unsigned short* Vw = Kw + (size_t)BB * NN * 16;      // [B][C][N]  bf16

    proj_kernel<<<256, 256, 0, stream>>>(x, Wq, bq, Wk, bk, Wv, bv, Qw, Kw, Vw);
    attn_kernel<<<256, 1024, 0, stream>>>(Qw, Kw, Vw, x, gamma, out);
}

// Round 13
// 29.485 us; speedup vs baseline: 5.5554x; 1.0804x over previous
//
#include <hip/hip_runtime.h>

typedef short s16x8 __attribute__((ext_vector_type(8)));
typedef float f32x4 __attribute__((ext_vector_type(4)));
typedef float f32x16 __attribute__((ext_vector_type(16)));
typedef unsigned u32x4 __attribute__((ext_vector_type(4)));

#define BB 4
#define NN 4096
#define LOG2E 1.4426950408889634f

__device__ __forceinline__ unsigned short f2bf(float f) {
    unsigned int u = __builtin_bit_cast(unsigned int, f);
    u += 0x7fff + ((u >> 16) & 1);   // RNE
    return (unsigned short)(u >> 16);
}

// pack two f32 -> bf16x2 (truncation) in one v_perm; low half = first arg
__device__ __forceinline__ unsigned pk2(float lo, float hi) {
    return __builtin_amdgcn_perm(__builtin_bit_cast(unsigned, hi),
                                 __builtin_bit_cast(unsigned, lo), 0x07060302u);
}

// swap lanes[32:63] of a with lanes[0:31] of b
__device__ __forceinline__ void pl32swap(unsigned &a, unsigned &b) {
    asm volatile("v_permlane32_swap_b32 %0, %1" : "+v"(a), "+v"(b));
}

// ---------------------------------------------------------------------------
// Projection via MFMA. W packed as 80 rows (q 0-7 [pre-scaled by log2e],
// k 8-15, v 16-79). Outputs (bf16): Qw,Kw as [b][n][16] (k 8..15 = 0);
// Vc in CHUNKED layout [b][j=n>>3][c][n&7] so attention's PV A-fragment
// load is a fully-coalesced global_load_dwordx4 (no LDS needed).
// ---------------------------------------------------------------------------
__global__ __launch_bounds__(256) void proj_kernel(
    const float* __restrict__ x,
    const float* __restrict__ Wq, const float* __restrict__ bq,
    const float* __restrict__ Wk, const float* __restrict__ bk,
    const float* __restrict__ Wv, const float* __restrict__ bv,
    unsigned short* __restrict__ Qw, unsigned short* __restrict__ Kw,
    unsigned short* __restrict__ Vc)
{
    __shared__ __attribute__((aligned(16))) unsigned short sW[80 * 72];
    __shared__ __attribute__((aligned(16))) unsigned short xT[64 * 72]; // reused as sV
    __shared__ float sb[80];

    int tid = threadIdx.x;
    int b  = blockIdx.x >> 6;
    int n0 = (blockIdx.x & 63) << 6;

    for (int i = tid; i < 1280; i += 256) {
        int o = i >> 4, c4 = (i & 15) << 2;
        const float* src = (o < 8) ? &Wq[o * 64 + c4]
                         : ((o < 16) ? &Wk[(o - 8) * 64 + c4]
                                     : &Wv[(o - 16) * 64 + c4]);
        float4 v = *(const float4*)src;
        float sc = (o < 8) ? LOG2E : 1.f;
        sW[o * 72 + c4 + 0] = f2bf(v.x * sc);
        sW[o * 72 + c4 + 1] = f2bf(v.y * sc);
        sW[o * 72 + c4 + 2] = f2bf(v.z * sc);
        sW[o * 72 + c4 + 3] = f2bf(v.w * sc);
    }
    if (tid < 80)
        sb[tid] = (tid < 8) ? bq[tid] * LOG2E
                            : ((tid < 16) ? bk[tid - 8] : bv[tid - 16]);
    for (int i = tid; i < 1024; i += 256) {
        int c = i >> 4, p4 = (i & 15) << 2;
        float4 v = *(const float4*)&x[(((size_t)b * 64 + c) << 12) + n0 + p4];
        xT[(p4 + 0) * 72 + c] = f2bf(v.x);
        xT[(p4 + 1) * 72 + c] = f2bf(v.y);
        xT[(p4 + 2) * 72 + c] = f2bf(v.z);
        xT[(p4 + 3) * 72 + c] = f2bf(v.w);
    }
    __syncthreads();

    int w = tid >> 6, l = tid & 63, g = l >> 4, q16 = l & 15;
    int pix = w * 16 + q16;

    s16x8 bf0 = *(const s16x8*)&xT[pix * 72 + g * 8];
    s16x8 bf1 = *(const s16x8*)&xT[pix * 72 + 32 + g * 8];

    s16x8 a0[5], a1[5];
#pragma unroll
    for (int ot = 0; ot < 5; ++ot) {
        a0[ot] = *(const s16x8*)&sW[(ot * 16 + q16) * 72 + g * 8];
        a1[ot] = *(const s16x8*)&sW[(ot * 16 + q16) * 72 + 32 + g * 8];
    }
    __syncthreads();   // xT frags consumed; recycle as sV

    unsigned short* sV = xT;
    size_t base16 = ((size_t)(b << 12) + n0 + pix) << 4;

#pragma unroll
    for (int ot = 0; ot < 5; ++ot) {
        f32x4 acc = {0.f, 0.f, 0.f, 0.f};
        acc = __builtin_amdgcn_mfma_f32_16x16x32_bf16(a0[ot], bf0, acc, 0, 0, 0);
        acc = __builtin_amdgcn_mfma_f32_16x16x32_bf16(a1[ot], bf1, acc, 0, 0, 0);
#pragma unroll
        for (int r = 0; r < 4; ++r) {
            int orow = ot * 16 + g * 4 + r;
            unsigned short hv = f2bf(acc[r] + sb[orow]);
            if (ot == 0) {
                if (orow < 8) {
                    Qw[base16 + orow] = hv;
                    Qw[base16 + orow + 8] = 0;
                } else {
                    Kw[base16 + orow - 8] = hv;
                    Kw[base16 + orow] = 0;
                }
            } else {
                sV[(orow - 16) * 72 + pix] = hv;
            }
        }
    }
    __syncthreads();

    // chunked V stores: Vc[b][j][c][8], 16B per (j,c)
#pragma unroll
    for (int i = tid; i < 512; i += 256) {
        int jj = i >> 6, c = i & 63;
        u32x4 v = *(const u32x4*)&sV[c * 72 + jj * 8];
        int jglob = ((blockIdx.x & 63) << 3) + jj;
        *(u32x4*)&Vc[(((size_t)b * 512 + jglob) * 64 + c) * 8] = v;
    }
}

// ---------------------------------------------------------------------------
// Flash attention, 32x32x16 MFMA, in-register P, NO LDS / NO BARRIERS in
// the main loop: V read directly from L2 in chunked layout (coalesced),
// K/V prefetched one chunk ahead into registers (rotating prefetch).
// Block = 512 thr = 8 waves = 32 queries x 8-way key split.
// Merge via small LDS rotation at the end only. (R9 structure, probe-free.)
// ---------------------------------------------------------------------------
template <int REPS>
__global__ __launch_bounds__(512, 2) void attn_t(
    const unsigned short* __restrict__ Qw, const unsigned short* __restrict__ Kw,
    const unsigned short* __restrict__ Vc, const float* __restrict__ x,
    const float* __restrict__ gamma, float* __restrict__ outp)
{
    __shared__ __attribute__((aligned(16))) float sO[64 * 36];
    __shared__ float sL[8 * 32];
    __shared__ float sGL[32];

    int tid = threadIdx.x;
    int w = tid >> 6, l = tid & 63, r31 = l & 31, hi = l >> 5;
    // XCD-aware remap: xcd = blockIdx%8 serves batch xcd>>1 (K/Q/V L2-resident)
    int p = blockIdx.x;
    int xcd = p & 7, kgrp = p >> 3;
    int b = xcd >> 1;
    int n0 = (((kgrp << 1) | (xcd & 1))) << 5;
    float gm = gamma[0];

    // Q fragment (32 queries of this block)
    s16x8 qf = *(const s16x8*)((const char*)Qw + ((size_t)b << 17)
                               + ((size_t)(n0 + r31) << 5) + (hi << 4));
    // K: wave w's 512-key slice; per chunk +ch*1024B
    const char* KbW = (const char*)Kw + ((size_t)b << 17) + (w << 14)
                    + (r31 << 5) + (hi << 4);
    // V chunked: wave w's slice; per chunk +ch*4096B; A1 +2048, B0 +512, B1 +2560
    const char* VcB = (const char*)Vc + ((size_t)b << 19) + (w << 16)
                    + (hi << 10) + (r31 << 4);

    f32x16 zz;
#pragma unroll
    for (int i = 0; i < 16; ++i) zz[i] = 0.f;

    for (int rep = 0; rep < REPS; ++rep) {
        f32x16 acc0, acc1;
#pragma unroll
        for (int i = 0; i < 16; ++i) { acc0[i] = 0.f; acc1[i] = 0.f; }
        float la = 0.f;

        s16x8 cK  = *(const s16x8*)(KbW);
        s16x8 cA0 = *(const s16x8*)(VcB);
        s16x8 cA1 = *(const s16x8*)(VcB + 2048);
        s16x8 cB0 = *(const s16x8*)(VcB + 512);
        s16x8 cB1 = *(const s16x8*)(VcB + 2560);

#pragma unroll
        for (int ch = 0; ch < 16; ++ch) {
            // prefetch chunk ch+1 (used next iteration; ~full-chunk latency cover)
            s16x8 nK = cK, nA0 = cA0, nA1 = cA1, nB0 = cB0, nB1 = cB1;
            if (ch < 15) {
                const char* pk = KbW + ((ch + 1) << 10);
                const char* pv = VcB + ((ch + 1) << 12);
                nK  = *(const s16x8*)(pk);
                nA0 = *(const s16x8*)(pv);
                nA1 = *(const s16x8*)(pv + 2048);
                nB0 = *(const s16x8*)(pv + 512);
                nB1 = *(const s16x8*)(pv + 2560);
            }

            f32x16 E = __builtin_amdgcn_mfma_f32_32x32x16_bf16(cK, qf, zz, 0, 0, 0);
#pragma unroll
            for (int i = 0; i < 16; ++i) E[i] = __builtin_amdgcn_exp2f(E[i]);
            la += (((E[0] + E[1]) + (E[2] + E[3])) + ((E[4] + E[5]) + (E[6] + E[7])))
                + (((E[8] + E[9]) + (E[10] + E[11])) + ((E[12] + E[13]) + (E[14] + E[15])));

            unsigned x0 = pk2(E[0], E[1]),   x1 = pk2(E[2], E[3]);
            unsigned x2 = pk2(E[4], E[5]),   x3 = pk2(E[6], E[7]);
            unsigned x4 = pk2(E[8], E[9]),   x5 = pk2(E[10], E[11]);
            unsigned x6 = pk2(E[12], E[13]), x7 = pk2(E[14], E[15]);
            pl32swap(x0, x2); pl32swap(x1, x3);
            pl32swap(x4, x6); pl32swap(x5, x7);
            u32x4 u0 = {x0, x1, x2, x3}, u1 = {x4, x5, x6, x7};
            s16x8 pf0 = __builtin_bit_cast(s16x8, u0);
            s16x8 pf1 = __builtin_bit_cast(s16x8, u1);

            acc0 = __builtin_amdgcn_mfma_f32_32x32x16_bf16(cA0, pf0, acc0, 0, 0, 0);
            acc0 = __builtin_amdgcn_mfma_f32_32x32x16_bf16(cA1, pf1, acc0, 0, 0, 0);
            acc1 = __builtin_amdgcn_mfma_f32_32x32x16_bf16(cB0, pf0, acc1, 0, 0, 0);
            acc1 = __builtin_amdgcn_mfma_f32_32x32x16_bf16(cB1, pf1, acc1, 0, 0, 0);

            cK = nK; cA0 = nA0; cA1 = nA1; cB0 = nB0; cB1 = nB1;
        }

        // ---- denominators ----
        la += __shfl_xor(la, 32);
        if (l < 32) sL[w * 32 + l] = la;

        // ---- rotation merge into sO (8 bands x 8 channels), stride 36 ----
#pragma unroll
        for (int s = 0; s < 8; ++s) {
            __syncthreads();
#pragma unroll
            for (int B = 0; B < 8; ++B) {
                if (((w + s) & 7) == B) {
                    const int R2 = B & 3;
                    float e0 = (B < 4) ? acc0[R2 * 4 + 0] : acc1[R2 * 4 + 0];
                    float e1 = (B < 4) ? acc0[R2 * 4 + 1] : acc1[R2 * 4 + 1];
                    float e2 = (B < 4) ? acc0[R2 * 4 + 2] : acc1[R2 * 4 + 2];
                    float e3 = (B < 4) ? acc0[R2 * 4 + 3] : acc1[R2 * 4 + 3];
                    float* pp = &sO[(B * 8 + hi * 4) * 36 + r31];
                    if (s == 0) {
                        pp[0] = e0; pp[36] = e1; pp[72] = e2; pp[108] = e3;
                    } else {
                        pp[0] += e0; pp[36] += e1; pp[72] += e2; pp[108] += e3;
                    }
                }
            }
        }
        __syncthreads();

        if (tid < 32) {
            float L = 0.f;
#pragma unroll
            for (int wk2 = 0; wk2 < 8; ++wk2) L += sL[wk2 * 32 + tid];
            sGL[tid] = gm / L;
        }
        __syncthreads();

        // ---- epilogue: 512 threads x one float4 ----
        {
            int c = tid >> 3, qc = tid & 7;
            float4 o4 = *(const float4*)&sO[c * 36 + qc * 4];
            float4 g4 = *(const float4*)&sGL[qc * 4];
            size_t idx = (((size_t)b * 64 + c) << 12) + n0 + qc * 4;
            float4 x4v = *(const float4*)&x[idx];
            o4.x = o4.x * g4.x + x4v.x;
            o4.y = o4.y * g4.y + x4v.y;
            o4.z = o4.z * g4.z + x4v.z;
            o4.w = o4.w * g4.w + x4v.w;
            *(float4*)&outp[idx] = o4;
        }
        if (REPS > 1) __syncthreads();
    }
}

extern "C" void kernel_launch(void* const* d_in, const int* in_sizes, int n_in,
                              void* d_out, int out_size, void* d_ws, size_t ws_size,
                              hipStream_t stream) {
    const float* x     = (const float*)d_in[0];
    const float* Wq    = (const float*)d_in[1];
    const float* bq    = (const float*)d_in[2];
    const float* Wk    = (const float*)d_in[3];
    const float* bk    = (const float*)d_in[4];
    const float* Wv    = (const float*)d_in[5];
    const float* bv    = (const float*)d_in[6];
    const float* gamma = (const float*)d_in[7];
    float* out = (float*)d_out;

    unsigned short* Qw = (unsigned short*)d_ws;          // [B][N][16] bf16 (padded)
    unsigned short* Kw = Qw + (size_t)BB * NN * 16;      // [B][N][16] bf16 (padded)
    unsigned short* Vc = Kw + (size_t)BB * NN * 16;      // [B][N/8][C][8] bf16

    proj_kernel<<<256, 256, 0, stream>>>(x, Wq, bq, Wk, bk, Wv, bv, Qw, Kw, Vc);
    attn_t<1><<<512, 512, 0, stream>>>(Qw, Kw, Vc, x, gamma, out);
}